// Round 4
// baseline (394.967 us; speedup 1.0000x reference)
//
#include <hip/hip_runtime.h>

// SymHQLinear: out[8192,4096] = x @ W^T; W[4096,4096] dequantized from
// codebook[4096,8] + per-row scales + packed sign bits.
#define M_ 8192   // TOKENS
#define N_ 4096   // OUT
#define K_ 4096   // IN

typedef __bf16 bf16x8 __attribute__((ext_vector_type(8)));
typedef float  f32x4  __attribute__((ext_vector_type(4)));
typedef float  f32x16 __attribute__((ext_vector_type(16)));

__device__ __forceinline__ unsigned short f2bf(float f) {
  unsigned u = __builtin_bit_cast(unsigned, f);
  unsigned r = 0x7fffu + ((u >> 16) & 1u);
  return (unsigned short)((u + r) >> 16);
}

// ---------------------------------------------------------------------------
// Kernel 1: dequantize W -> bf16 [N_][K_]
// ---------------------------------------------------------------------------
__global__ __launch_bounds__(256) void dequant_w_kernel(
    const float* __restrict__ cb, const float* __restrict__ scales,
    const int* __restrict__ idx, const int* __restrict__ signs,
    unsigned short* __restrict__ Wb)
{
  const int g   = blockIdx.x * 256 + threadIdx.x;
  const int row = g >> 9;                           // 512 groups per row
  const int code = idx[g];
  const int sb   = signs[g];
  const float s  = scales[row];
  const float* cv = cb + code * 8;

  unsigned short h[8];
#pragma unroll
  for (int j = 0; j < 8; ++j) {
    float v = cv[j] * s;
    if (!((sb >> (7 - j)) & 1)) v = -v;
    h[j] = f2bf(v);
  }
  uint4 o;
  o.x = (unsigned)h[0] | ((unsigned)h[1] << 16);
  o.y = (unsigned)h[2] | ((unsigned)h[3] << 16);
  o.z = (unsigned)h[4] | ((unsigned)h[5] << 16);
  o.w = (unsigned)h[6] | ((unsigned)h[7] << 16);
  *(uint4*)(Wb + (size_t)g * 8) = o;
}

// ---------------------------------------------------------------------------
// Kernel 2: cast x fp32 -> bf16
// ---------------------------------------------------------------------------
__global__ __launch_bounds__(256) void cvt_x_kernel(
    const float* __restrict__ x, unsigned short* __restrict__ Xb)
{
  const size_t i = (size_t)blockIdx.x * 256 + threadIdx.x;
  const f32x4* px = (const f32x4*)(x + i * 8);
  f32x4 a = px[0], b = px[1];
  uint4 o;
  o.x = (unsigned)f2bf(a[0]) | ((unsigned)f2bf(a[1]) << 16);
  o.y = (unsigned)f2bf(a[2]) | ((unsigned)f2bf(a[3]) << 16);
  o.z = (unsigned)f2bf(b[0]) | ((unsigned)f2bf(b[1]) << 16);
  o.w = (unsigned)f2bf(b[2]) | ((unsigned)f2bf(b[3]) << 16);
  *(uint4*)(Xb + i * 8) = o;
}

// ---------------------------------------------------------------------------
// Kernel 3: 256x256x64 GEMM, pipelined 4-phase schedule, 32x32x16 MFMA.
// (m119: 32x32x16 = 2495 TF ubench vs 16x16x32 = 2176 -> ~15% less MFMA-pipe
// time for identical FLOPs.) Schedule identical to R3: phase p issues
// ds_reads for phase p+1 with counted lgkmcnt; staging GLDS at P1/P2/P3;
// vmcnt(2) once per tile.
// Per wave (2M x 4N of 8 waves): output 128x64 = 4 mrep x 2 nrep of 32x32.
// Phases: P0 (m0,m1)xn0, P1 (m0,m1)xn1, P2 (m2,m3)xn0, P3 (m2,m3)xn1.
// Reads:  P0 bh(4), P1 aq1(8), P2 next aq0'(8), P3 next bl'(4).
// ---------------------------------------------------------------------------
#define BM 256
#define BN 256
#define BK 64
#define NT (K_ / BK)          // 64 K-tiles
#define HTE 8192              // bf16 elems per half-tile (128 x 64)

#define GLDS(g, l) __builtin_amdgcn_global_load_lds( \
    (const __attribute__((address_space(1))) void*)(g), \
    (__attribute__((address_space(3))) void*)(l), 16, 0, 0)

#define LGKM_WAIT(n) do { \
    asm volatile("s_waitcnt lgkmcnt(" #n ")" ::: "memory"); \
    __builtin_amdgcn_sched_barrier(0); \
  } while (0)

// A-frag (32x32x16): row = base + l31, k-chunk = ks*2 + hi (8 bf16 each).
// LDS elem offset with 16B-chunk swizzle: row*64 + ((chunk ^ (row&7)) * 8).
#define FRAG(base_ptr, rowexpr, kc) \
  (*(const bf16x8*)(const void*)((base_ptr) + (size_t)(rowexpr) * 64 + ((((kc)) ^ ((rowexpr) & 7)) * 8)))

// MODE: 0 = steady, 1 = t==NT-2 (no stage, vmcnt(0)), 2 = t==NT-1 (tail)
template<int MODE>
__device__ __forceinline__ void tile_step(
    int t, unsigned short (*lds)[HTE], f32x16 (&acc)[4][2],
    bf16x8 (&aq0)[2][4], bf16x8 (&aq1)[2][4],
    bf16x8 (&bl)[4], bf16x8 (&bh)[4],
    const unsigned short* __restrict__ Ag,
    const unsigned short* __restrict__ Bg,
    int wm, int wnl, int bsel, int l31, int hi,
    int w, int lane, int srow, int scw8)
{
  unsigned short* Lb = lds[(t & 1) * 4];
  unsigned short* Ln = lds[((t + 1) & 1) * 4];
  const unsigned short* Ab = Lb + wm * HTE;
  const unsigned short* Bb = Lb + (2 + bsel) * HTE;
  const unsigned short* An = Ln + wm * HTE;
  const unsigned short* Bn = Ln + (2 + bsel) * HTE;
  const int dst  = (w * 128 + lane) * 8;
  const int dst1 = (w * 128 + 64 + lane) * 8;

  const int ar0 = 0 * 32 + l31, ar1 = 1 * 32 + l31;   // aq0 rows
  const int ar2 = 64 + l31,     ar3 = 96 + l31;       // aq1 rows
  const int bc0 = wnl * 64 + l31;                     // bl col (n0)
  const int bc1 = wnl * 64 + 32 + l31;                // bh col (n1)

  // ========== P0: read bh (for P1); MFMA (m0,m1) x n0 ==========
#pragma unroll
  for (int ks = 0; ks < 4; ++ks)
    bh[ks] = FRAG(Bb, bc1, ks * 2 + hi);
  __builtin_amdgcn_s_barrier();
  LGKM_WAIT(4);                       // aq0 + bl (issued prev P2/P3) ready
  __builtin_amdgcn_s_setprio(1);
#pragma unroll
  for (int m = 0; m < 2; ++m)
#pragma unroll
    for (int ks = 0; ks < 4; ++ks)
      acc[m][0] = __builtin_amdgcn_mfma_f32_32x32x16_bf16(aq0[m][ks], bl[ks], acc[m][0], 0, 0, 0);
  __builtin_amdgcn_s_setprio(0);
  __builtin_amdgcn_s_barrier();

  // ===== P1: read aq1 (for P2); stage r2; MFMA (m0,m1) x n1; vmcnt =====
#pragma unroll
  for (int ks = 0; ks < 4; ++ks) {
    aq1[0][ks] = FRAG(Ab, ar2, ks * 2 + hi);
    aq1[1][ks] = FRAG(Ab, ar3, ks * 2 + hi);
  }
  if (MODE == 0) {
    GLDS(Bg + (size_t)(srow) * K_ + (t + 2) * BK + scw8,     Lb + 2 * HTE + dst);
    GLDS(Bg + (size_t)(srow + 8) * K_ + (t + 2) * BK + scw8, Lb + 2 * HTE + dst1);
  }
  __builtin_amdgcn_s_barrier();
  LGKM_WAIT(8);                       // bh (issued P0) ready
  __builtin_amdgcn_s_setprio(1);
#pragma unroll
  for (int m = 0; m < 2; ++m)
#pragma unroll
    for (int ks = 0; ks < 4; ++ks)
      acc[m][1] = __builtin_amdgcn_mfma_f32_32x32x16_bf16(aq0[m][ks], bh[ks], acc[m][1], 0, 0, 0);
  __builtin_amdgcn_s_setprio(0);
  if (MODE == 0)
    asm volatile("s_waitcnt vmcnt(2)" ::: "memory");   // next-tile buffer landed
  else if (MODE == 1)
    asm volatile("s_waitcnt vmcnt(0)" ::: "memory");
  __builtin_amdgcn_s_barrier();

  // ===== P2: read next aq0'; stage r3; MFMA (m2,m3) x n0 =====
  if (MODE < 2) {
#pragma unroll
    for (int ks = 0; ks < 4; ++ks) {
      aq0[0][ks] = FRAG(An, ar0, ks * 2 + hi);
      aq0[1][ks] = FRAG(An, ar1, ks * 2 + hi);
    }
  }
  if (MODE == 0) {
    GLDS(Bg + (size_t)(128 + srow) * K_ + (t + 2) * BK + scw8,     Lb + 3 * HTE + dst);
    GLDS(Bg + (size_t)(128 + srow + 8) * K_ + (t + 2) * BK + scw8, Lb + 3 * HTE + dst1);
  }
  __builtin_amdgcn_s_barrier();
  if (MODE < 2) { LGKM_WAIT(8); } else { LGKM_WAIT(0); }   // aq1 ready
  __builtin_amdgcn_s_setprio(1);
#pragma unroll
  for (int m = 0; m < 2; ++m)
#pragma unroll
    for (int ks = 0; ks < 4; ++ks)
      acc[2 + m][0] = __builtin_amdgcn_mfma_f32_32x32x16_bf16(aq1[m][ks], bl[ks], acc[2 + m][0], 0, 0, 0);
  __builtin_amdgcn_s_setprio(0);
  __builtin_amdgcn_s_barrier();

  // ===== P3: read next bl'; stage r0+r1; MFMA (m2,m3) x n1 =====
  if (MODE < 2) {
#pragma unroll
    for (int ks = 0; ks < 4; ++ks)
      bl[ks] = FRAG(Bn, bc0, ks * 2 + hi);
  }
  if (MODE == 0) {
    GLDS(Ag + (size_t)(srow) * K_ + (t + 2) * BK + scw8,           Lb + 0 * HTE + dst);
    GLDS(Ag + (size_t)(srow + 8) * K_ + (t + 2) * BK + scw8,       Lb + 0 * HTE + dst1);
    GLDS(Ag + (size_t)(128 + srow) * K_ + (t + 2) * BK + scw8,     Lb + 1 * HTE + dst);
    GLDS(Ag + (size_t)(128 + srow + 8) * K_ + (t + 2) * BK + scw8, Lb + 1 * HTE + dst1);
  }
  __builtin_amdgcn_s_barrier();
  // no lgkm wait: aq1 confirmed at P2's wait, bh at P1's wait
  __builtin_amdgcn_s_setprio(1);
#pragma unroll
  for (int m = 0; m < 2; ++m)
#pragma unroll
    for (int ks = 0; ks < 4; ++ks)
      acc[2 + m][1] = __builtin_amdgcn_mfma_f32_32x32x16_bf16(aq1[m][ks], bh[ks], acc[2 + m][1], 0, 0, 0);
  __builtin_amdgcn_s_setprio(0);
  __builtin_amdgcn_s_barrier();
}

__global__ __launch_bounds__(512, 2) void gemm256_kernel(
    const unsigned short* __restrict__ A,   // Xb [M_][K_]
    const unsigned short* __restrict__ B,   // Wb [N_][K_]
    float* __restrict__ C)
{
  __shared__ unsigned short lds[8][HTE];    // 128 KiB

  // XCD-aware bijective swizzle (nwg = 512, 512 % 8 == 0)
  const int nwg = (M_ / BM) * (N_ / BN);
  const int bid = blockIdx.x;
  const int wg  = (bid % 8) * (nwg / 8) + bid / 8;
  const int tn  = wg % (N_ / BN);
  const int tm  = wg / (N_ / BN);
  const int brow = tm * BM, bcol = tn * BN;

  const int tid  = threadIdx.x;
  const int lane = tid & 63, w = tid >> 6;
  const int wm   = w >> 2, wn = w & 3;      // 2 (M) x 4 (N)
  const int wnl  = wn & 1, bsel = wn >> 1;
  const int l31  = lane & 31, hi = lane >> 5;
  const int srow = w * 16 + (lane >> 3);
  const int scw8 = ((lane & 7) ^ (lane >> 3)) * 8;   // inverse-swizzled col

  const unsigned short* Ag = A + (size_t)brow * K_;
  const unsigned short* Bg = B + (size_t)bcol * K_;

  f32x16 acc[4][2];
#pragma unroll
  for (int m = 0; m < 4; ++m)
#pragma unroll
    for (int n = 0; n < 2; ++n)
      acc[m][n] = (f32x16)(0.f);

  // prologue: stage tile 0 -> buf0 (first!), tile 1 -> buf1
#pragma unroll
  for (int tt = 0; tt < 2; ++tt) {
    unsigned short* Lb = lds[tt * 4];
#pragma unroll
    for (int i = 0; i < 2; ++i) {
      const int r = srow + i * 8;
      const int d = (w * 128 + i * 64 + lane) * 8;
      GLDS(Ag + (size_t)r * K_ + tt * BK + scw8,         Lb + 0 * HTE + d);
      GLDS(Ag + (size_t)(128 + r) * K_ + tt * BK + scw8, Lb + 1 * HTE + d);
      GLDS(Bg + (size_t)r * K_ + tt * BK + scw8,         Lb + 2 * HTE + d);
      GLDS(Bg + (size_t)(128 + r) * K_ + tt * BK + scw8, Lb + 3 * HTE + d);
    }
  }
  asm volatile("s_waitcnt vmcnt(8)" ::: "memory");     // tile 0 landed
  __builtin_amdgcn_s_barrier();

  // pre-read tile0 P0 operands: aq0 (m0,m1) + bl (n0), buf0
  bf16x8 aq0[2][4], aq1[2][4], bl[4], bh[4];
  {
    const unsigned short* Ab = lds[0] + wm * HTE;
    const unsigned short* Bb = lds[0] + (2 + bsel) * HTE;
    const int ar0 = l31, ar1 = 32 + l31, bc0 = wnl * 64 + l31;
#pragma unroll
    for (int ks = 0; ks < 4; ++ks) {
      aq0[0][ks] = FRAG(Ab, ar0, ks * 2 + hi);
      aq0[1][ks] = FRAG(Ab, ar1, ks * 2 + hi);
      bl[ks]     = FRAG(Bb, bc0, ks * 2 + hi);
    }
  }

  for (int t = 0; t < NT - 2; ++t)
    tile_step<0>(t, lds, acc, aq0, aq1, bl, bh, Ag, Bg,
                 wm, wnl, bsel, l31, hi, w, lane, srow, scw8);
  tile_step<1>(NT - 2, lds, acc, aq0, aq1, bl, bh, Ag, Bg,
               wm, wnl, bsel, l31, hi, w, lane, srow, scw8);
  tile_step<2>(NT - 1, lds, acc, aq0, aq1, bl, bh, Ag, Bg,
               wm, wnl, bsel, l31, hi, w, lane, srow, scw8);

  // epilogue: 32x32 C/D layout (m74/m101): col = lane&31,
  // row = (reg&3) + 8*(reg>>2) + 4*(lane>>5)
  const int ccol = bcol + wn * 64 + l31;
#pragma unroll
  for (int m = 0; m < 4; ++m)
#pragma unroll
    for (int n = 0; n < 2; ++n)
#pragma unroll
      for (int r = 0; r < 16; ++r) {
        const int row = brow + wm * 128 + m * 32 + (r & 3) + 8 * (r >> 2) + 4 * hi;
        C[(size_t)row * N_ + ccol + n * 32] = acc[m][n][r];
      }
}

// ---------------------------------------------------------------------------
// Fallback (ws too small): fp32 tiled GEMM with on-the-fly dequant
// ---------------------------------------------------------------------------
__global__ __launch_bounds__(256) void fallback_kernel(
    const float* __restrict__ x, const float* __restrict__ cb,
    const float* __restrict__ scales, const int* __restrict__ idx,
    const int* __restrict__ signs, float* __restrict__ out)
{
  __shared__ float Xs[32][33];
  __shared__ float Ws[32][33];
  const int t = threadIdx.x;
  const int tx = t & 31, ty = t >> 5;
  const int brow = blockIdx.y * 32, bcol = blockIdx.x * 32;
  float acc[4] = {0.f, 0.f, 0.f, 0.f};

  for (int k0 = 0; k0 < K_; k0 += 32) {
    for (int l = t; l < 1024; l += 256) {
      const int r = l >> 5, c = l & 31;
      Xs[r][c] = x[(size_t)(brow + r) * K_ + k0 + c];
      const int n = bcol + r;
      const size_t flat = (size_t)n * K_ + (k0 + c);
      const int g = (int)(flat >> 3), j = (int)(flat & 7);
      float wv = cb[idx[g] * 8 + j] * scales[n];
      if (!((signs[g] >> (7 - j)) & 1)) wv = -wv;
      Ws[r][c] = wv;
    }
    __syncthreads();
#pragma unroll
    for (int kk = 0; kk < 32; ++kk) {
      const float wv = Ws[tx][kk];
      acc[0] += Xs[ty][kk] * wv;
      acc[1] += Xs[ty + 8][kk] * wv;
      acc[2] += Xs[ty + 16][kk] * wv;
      acc[3] += Xs[ty + 24][kk] * wv;
    }
    __syncthreads();
  }
#pragma unroll
  for (int q = 0; q < 4; ++q)
    out[(size_t)(brow + ty + 8 * q) * N_ + bcol + tx] = acc[q];
}

// ---------------------------------------------------------------------------
extern "C" void kernel_launch(void* const* d_in, const int* in_sizes, int n_in,
                              void* d_out, int out_size, void* d_ws, size_t ws_size,
                              hipStream_t stream)
{
  const float* x      = (const float*)d_in[0];
  const float* cb     = (const float*)d_in[1];
  const float* scales = (const float*)d_in[2];
  const int*   idx    = (const int*)d_in[3];
  const int*   signs  = (const int*)d_in[4];
  float* out = (float*)d_out;

  const size_t wbytes = (size_t)N_ * K_ * 2;
  const size_t xbytes = (size_t)M_ * K_ * 2;

  if (ws_size >= wbytes + xbytes) {
    unsigned short* Wb = (unsigned short*)d_ws;
    unsigned short* Xb = (unsigned short*)((char*)d_ws + wbytes);
    dequant_w_kernel<<<(N_ * K_ / 8) / 256, 256, 0, stream>>>(cb, scales, idx, signs, Wb);
    cvt_x_kernel<<<(M_ * K_ / 8) / 256, 256, 0, stream>>>(x, Xb);
    gemm256_kernel<<<(M_ / BM) * (N_ / BN), 512, 0, stream>>>(Xb, Wb, out);
  } else {
    fallback_kernel<<<dim3(N_ / 32, M_ / 32), 256, 0, stream>>>(x, cb, scales, idx, signs, out);
  }
}

// Round 6
// 289.496 us; speedup vs baseline: 1.3643x; 1.3643x over previous
//
#include <hip/hip_runtime.h>

// SymHQLinear: out[8192,4096] = x @ W^T; W[4096,4096] dequantized from
// codebook[4096,8] + per-row scales + packed sign bits.
#define M_ 8192   // TOKENS
#define N_ 4096   // OUT
#define K_ 4096   // IN

typedef __bf16 bf16x8 __attribute__((ext_vector_type(8)));
typedef float  f32x4  __attribute__((ext_vector_type(4)));

__device__ __forceinline__ unsigned short f2bf(float f) {
  unsigned u = __builtin_bit_cast(unsigned, f);
  unsigned r = 0x7fffu + ((u >> 16) & 1u);
  return (unsigned short)((u + r) >> 16);
}

// ---------------------------------------------------------------------------
// Kernel 1: dequantize W -> bf16 [N_][K_]
// ---------------------------------------------------------------------------
__global__ __launch_bounds__(256) void dequant_w_kernel(
    const float* __restrict__ cb, const float* __restrict__ scales,
    const int* __restrict__ idx, const int* __restrict__ signs,
    unsigned short* __restrict__ Wb)
{
  const int g   = blockIdx.x * 256 + threadIdx.x;
  const int row = g >> 9;                           // 512 groups per row
  const int code = idx[g];
  const int sb   = signs[g];
  const float s  = scales[row];
  const float* cv = cb + code * 8;

  unsigned short h[8];
#pragma unroll
  for (int j = 0; j < 8; ++j) {
    float v = cv[j] * s;
    if (!((sb >> (7 - j)) & 1)) v = -v;
    h[j] = f2bf(v);
  }
  uint4 o;
  o.x = (unsigned)h[0] | ((unsigned)h[1] << 16);
  o.y = (unsigned)h[2] | ((unsigned)h[3] << 16);
  o.z = (unsigned)h[4] | ((unsigned)h[5] << 16);
  o.w = (unsigned)h[6] | ((unsigned)h[7] << 16);
  *(uint4*)(Wb + (size_t)g * 8) = o;
}

// ---------------------------------------------------------------------------
// Kernel 2: cast x fp32 -> bf16
// ---------------------------------------------------------------------------
__global__ __launch_bounds__(256) void cvt_x_kernel(
    const float* __restrict__ x, unsigned short* __restrict__ Xb)
{
  const size_t i = (size_t)blockIdx.x * 256 + threadIdx.x;
  const f32x4* px = (const f32x4*)(x + i * 8);
  f32x4 a = px[0], b = px[1];
  uint4 o;
  o.x = (unsigned)f2bf(a[0]) | ((unsigned)f2bf(a[1]) << 16);
  o.y = (unsigned)f2bf(a[2]) | ((unsigned)f2bf(a[3]) << 16);
  o.z = (unsigned)f2bf(b[0]) | ((unsigned)f2bf(b[1]) << 16);
  o.w = (unsigned)f2bf(b[2]) | ((unsigned)f2bf(b[3]) << 16);
  *(uint4*)(Xb + i * 8) = o;
}

// ---------------------------------------------------------------------------
// Kernel 3: 256x256x64 GEMM, 16x16x32 MFMA, minimal-sync (2 barriers/tile),
// R5-race FIXED: cross-buffer pre-reads moved AFTER mid-tile vmcnt+barrier.
//
// Tile t (steady), per wave -- invariant at entry: buf[t] visible; aq0,bl
// hold tile-t B0 operands (lgkm-confirmed):
//   issue bh(4), aq1(8) from Lb
//   B0: q0 x bl                       (no wait)
//   lgkm(8)  -> bh served
//   B1: q0 x bh
//   lgkm(0)  -> aq1 served; ALL my Lb reads now served
//   barrier#1  [+compiler memfence]   -> every wave's Lb reads served
//   GLDS x8 (t+2 -> Lb)               -> safe overwrite
//   vmcnt(8) -> my t+1 loads (issued t-1) drained; t+2's 8 stay in flight
//   barrier#2  [+memfence]            -> buf[t+1] visible to ALL waves
//   issue aq0'(8) from Ln             -> SAFE (the R5 race is gone)
//   B2: q1 x bl                       (bl dead after)
//   issue bl'(4) from Ln
//   B3: q1 x bh
//   lgkm(0)  -> aq0',bl' served       -> next tile's B0 invariant
// ---------------------------------------------------------------------------
#define BM 256
#define BN 256
#define BK 64
#define NT (K_ / BK)          // 64 K-tiles
#define HTE 8192              // bf16 elems per half-tile (128 x 64)

#define GLDS(g, l) __builtin_amdgcn_global_load_lds( \
    (const __attribute__((address_space(1))) void*)(g), \
    (__attribute__((address_space(3))) void*)(l), 16, 0, 0)

#define LGKM_WAIT(n) do { \
    asm volatile("s_waitcnt lgkmcnt(" #n ")" ::: "memory"); \
    __builtin_amdgcn_sched_barrier(0); \
  } while (0)

#define MEMFENCE asm volatile("" ::: "memory")

// MODE: 0 = steady, 1 = t==NT-2 (no GLDS, vmcnt(0)), 2 = t==NT-1 (tail)
template<int MODE>
__device__ __forceinline__ void tile_step(
    int t, unsigned short (*lds)[HTE], f32x4 (&acc)[8][4],
    bf16x8 (&aq0)[4][2], bf16x8 (&aq1)[4][2],
    bf16x8 (&bl)[2][2], bf16x8 (&bh)[2][2],
    const unsigned short* __restrict__ Ag,
    const unsigned short* __restrict__ Bg,
    int wm, int wnl, int bsel, int lrow, int hi2, int sw,
    int w, int lane, int srow, int scw8)
{
  unsigned short* Lb = lds[(t & 1) * 4];
  unsigned short* Ln = lds[((t + 1) & 1) * 4];
  const unsigned short* Ab = Lb + wm * HTE;
  const unsigned short* Bb = Lb + (2 + bsel) * HTE;
  const unsigned short* An = Ln + wm * HTE;
  const unsigned short* Bn = Ln + (2 + bsel) * HTE;
  const int dst  = (w * 128 + lane) * 8;
  const int dst1 = (w * 128 + 64 + lane) * 8;

  // ---- issue bh (4) FIRST, then aq1 (8); order pinned for counted waits ----
#pragma unroll
  for (int n = 0; n < 2; ++n)
#pragma unroll
    for (int ks = 0; ks < 2; ++ks)
      bh[n][ks] = *(const bf16x8*)(const void*)(
          Bb + (wnl * 64 + (2 + n) * 16 + lrow) * 64 + (((ks * 4 + hi2) ^ sw) * 8));
  __builtin_amdgcn_sched_barrier(0);
#pragma unroll
  for (int m = 0; m < 4; ++m)
#pragma unroll
    for (int ks = 0; ks < 2; ++ks)
      aq1[m][ks] = *(const bf16x8*)(const void*)(
          Ab + ((4 + m) * 16 + lrow) * 64 + (((ks * 4 + hi2) ^ sw) * 8));

  // ---- B0: q0 x bl (operands confirmed last tile) ----
  __builtin_amdgcn_s_setprio(1);
#pragma unroll
  for (int m = 0; m < 4; ++m)
#pragma unroll
    for (int n = 0; n < 2; ++n)
#pragma unroll
      for (int ks = 0; ks < 2; ++ks)
        acc[m][n] = __builtin_amdgcn_mfma_f32_16x16x32_bf16(aq0[m][ks], bl[n][ks], acc[m][n], 0, 0, 0);
  __builtin_amdgcn_s_setprio(0);

  LGKM_WAIT(8);                          // bh (oldest 4) served

  // ---- B1: q0 x bh ----
  __builtin_amdgcn_s_setprio(1);
#pragma unroll
  for (int m = 0; m < 4; ++m)
#pragma unroll
    for (int n = 0; n < 2; ++n)
#pragma unroll
      for (int ks = 0; ks < 2; ++ks)
        acc[m][2 + n] = __builtin_amdgcn_mfma_f32_16x16x32_bf16(aq0[m][ks], bh[n][ks], acc[m][2 + n], 0, 0, 0);
  __builtin_amdgcn_s_setprio(0);

  LGKM_WAIT(0);                          // aq1 served; all my Lb reads done

  // ---- barrier #1: every wave's Lb reads served -> Lb overwrite safe ----
  __builtin_amdgcn_s_barrier();
  MEMFENCE;
  if (MODE == 0) {
    GLDS(Bg + (size_t)(srow) * K_ + (t + 2) * BK + scw8,           Lb + 2 * HTE + dst);
    GLDS(Bg + (size_t)(srow + 8) * K_ + (t + 2) * BK + scw8,       Lb + 2 * HTE + dst1);
    GLDS(Bg + (size_t)(128 + srow) * K_ + (t + 2) * BK + scw8,     Lb + 3 * HTE + dst);
    GLDS(Bg + (size_t)(128 + srow + 8) * K_ + (t + 2) * BK + scw8, Lb + 3 * HTE + dst1);
    GLDS(Ag + (size_t)(srow) * K_ + (t + 2) * BK + scw8,           Lb + 0 * HTE + dst);
    GLDS(Ag + (size_t)(srow + 8) * K_ + (t + 2) * BK + scw8,       Lb + 0 * HTE + dst1);
    GLDS(Ag + (size_t)(128 + srow) * K_ + (t + 2) * BK + scw8,     Lb + 1 * HTE + dst);
    GLDS(Ag + (size_t)(128 + srow + 8) * K_ + (t + 2) * BK + scw8, Lb + 1 * HTE + dst1);
  }
  if (MODE == 0)      asm volatile("s_waitcnt vmcnt(8)" ::: "memory");  // t+1 landed (mine)
  else if (MODE == 1) asm volatile("s_waitcnt vmcnt(0)" ::: "memory");  // last loads landed
  __builtin_amdgcn_s_barrier();          // barrier #2: buf[t+1] visible to all
  MEMFENCE;

  // ---- pre-read next tile's q0 A-frags (SAFE: after vmcnt+barrier) ----
  if (MODE < 2) {
#pragma unroll
    for (int m = 0; m < 4; ++m)
#pragma unroll
      for (int ks = 0; ks < 2; ++ks)
        aq0[m][ks] = *(const bf16x8*)(const void*)(
            An + (m * 16 + lrow) * 64 + (((ks * 4 + hi2) ^ sw) * 8));
  }

  // ---- B2: q1 x bl ----
  __builtin_amdgcn_s_setprio(1);
#pragma unroll
  for (int m = 0; m < 4; ++m)
#pragma unroll
    for (int n = 0; n < 2; ++n)
#pragma unroll
      for (int ks = 0; ks < 2; ++ks)
        acc[4 + m][n] = __builtin_amdgcn_mfma_f32_16x16x32_bf16(aq1[m][ks], bl[n][ks], acc[4 + m][n], 0, 0, 0);
  __builtin_amdgcn_s_setprio(0);

  // ---- bl dead: pre-read next tile's B-lo ----
  if (MODE < 2) {
#pragma unroll
    for (int n = 0; n < 2; ++n)
#pragma unroll
      for (int ks = 0; ks < 2; ++ks)
        bl[n][ks] = *(const bf16x8*)(const void*)(
            Bn + (wnl * 64 + n * 16 + lrow) * 64 + (((ks * 4 + hi2) ^ sw) * 8));
  }

  // ---- B3: q1 x bh ----
  __builtin_amdgcn_s_setprio(1);
#pragma unroll
  for (int m = 0; m < 4; ++m)
#pragma unroll
    for (int n = 0; n < 2; ++n)
#pragma unroll
      for (int ks = 0; ks < 2; ++ks)
        acc[4 + m][2 + n] = __builtin_amdgcn_mfma_f32_16x16x32_bf16(aq1[m][ks], bh[n][ks], acc[4 + m][2 + n], 0, 0, 0);
  __builtin_amdgcn_s_setprio(0);

  if (MODE < 2) LGKM_WAIT(0);            // aq0', bl' served: next tile B0 ready
}

__global__ __launch_bounds__(512, 2) void gemm256_kernel(
    const unsigned short* __restrict__ A,   // Xb [M_][K_]
    const unsigned short* __restrict__ B,   // Wb [N_][K_]
    float* __restrict__ C)
{
  __shared__ unsigned short lds[8][HTE];    // 128 KiB

  // XCD-aware bijective swizzle (nwg = 512, 512 % 8 == 0)
  const int nwg = (M_ / BM) * (N_ / BN);
  const int bid = blockIdx.x;
  const int wg  = (bid % 8) * (nwg / 8) + bid / 8;
  const int tn  = wg % (N_ / BN);
  const int tm  = wg / (N_ / BN);
  const int brow = tm * BM, bcol = tn * BN;

  const int tid  = threadIdx.x;
  const int lane = tid & 63, w = tid >> 6;
  const int wm   = w >> 2, wn = w & 3;      // 2 (M) x 4 (N)
  const int wnl  = wn & 1, bsel = wn >> 1;
  const int lrow = lane & 15, hi2 = lane >> 4, sw = lrow & 7;
  const int srow = w * 16 + (lane >> 3);
  const int scw8 = ((lane & 7) ^ (lane >> 3)) * 8;   // inverse-swizzled col

  const unsigned short* Ag = A + (size_t)brow * K_;
  const unsigned short* Bg = B + (size_t)bcol * K_;

  f32x4 acc[8][4];
#pragma unroll
  for (int m = 0; m < 8; ++m)
#pragma unroll
    for (int n = 0; n < 4; ++n)
      acc[m][n] = f32x4{0.f, 0.f, 0.f, 0.f};

  // prologue: stage tile 0 -> buf0 (first!), tile 1 -> buf1
#pragma unroll
  for (int tt = 0; tt < 2; ++tt) {
    unsigned short* Lb = lds[tt * 4];
#pragma unroll
    for (int i = 0; i < 2; ++i) {
      const int r = srow + i * 8;
      const int d = (w * 128 + i * 64 + lane) * 8;
      GLDS(Ag + (size_t)r * K_ + tt * BK + scw8,         Lb + 0 * HTE + d);
      GLDS(Ag + (size_t)(128 + r) * K_ + tt * BK + scw8, Lb + 1 * HTE + d);
      GLDS(Bg + (size_t)r * K_ + tt * BK + scw8,         Lb + 2 * HTE + d);
      GLDS(Bg + (size_t)(128 + r) * K_ + tt * BK + scw8, Lb + 3 * HTE + d);
    }
  }
  asm volatile("s_waitcnt vmcnt(8)" ::: "memory");     // tile 0 landed
  __builtin_amdgcn_s_barrier();
  MEMFENCE;

  // pre-read tile0 B0 operands (aq0 quad0 + bl), buf0; confirm before loop
  bf16x8 aq0[4][2], aq1[4][2], bl[2][2], bh[2][2];
  {
    const unsigned short* Ab = lds[0] + wm * HTE;
    const unsigned short* Bb = lds[0] + (2 + bsel) * HTE;
#pragma unroll
    for (int m = 0; m < 4; ++m)
#pragma unroll
      for (int ks = 0; ks < 2; ++ks)
        aq0[m][ks] = *(const bf16x8*)(const void*)(
            Ab + (m * 16 + lrow) * 64 + (((ks * 4 + hi2) ^ sw) * 8));
#pragma unroll
    for (int n = 0; n < 2; ++n)
#pragma unroll
      for (int ks = 0; ks < 2; ++ks)
        bl[n][ks] = *(const bf16x8*)(const void*)(
            Bb + (wnl * 64 + n * 16 + lrow) * 64 + (((ks * 4 + hi2) ^ sw) * 8));
  }
  LGKM_WAIT(0);

  for (int t = 0; t < NT - 2; ++t)
    tile_step<0>(t, lds, acc, aq0, aq1, bl, bh, Ag, Bg,
                 wm, wnl, bsel, lrow, hi2, sw, w, lane, srow, scw8);
  tile_step<1>(NT - 2, lds, acc, aq0, aq1, bl, bh, Ag, Bg,
               wm, wnl, bsel, lrow, hi2, sw, w, lane, srow, scw8);
  tile_step<2>(NT - 1, lds, acc, aq0, aq1, bl, bh, Ag, Bg,
               wm, wnl, bsel, lrow, hi2, sw, w, lane, srow, scw8);

  // epilogue: C/D layout col = lane&15, row = (lane>>4)*4 + reg
  const int crow = brow + wm * 128 + hi2 * 4;
  const int ccol = bcol + wn * 64 + lrow;
#pragma unroll
  for (int m = 0; m < 8; ++m)
#pragma unroll
    for (int n = 0; n < 4; ++n)
#pragma unroll
      for (int r = 0; r < 4; ++r)
        C[(size_t)(crow + m * 16 + r) * N_ + ccol + n * 16] = acc[m][n][r];
}

// ---------------------------------------------------------------------------
// Fallback (ws too small): fp32 tiled GEMM with on-the-fly dequant
// ---------------------------------------------------------------------------
__global__ __launch_bounds__(256) void fallback_kernel(
    const float* __restrict__ x, const float* __restrict__ cb,
    const float* __restrict__ scales, const int* __restrict__ idx,
    const int* __restrict__ signs, float* __restrict__ out)
{
  __shared__ float Xs[32][33];
  __shared__ float Ws[32][33];
  const int t = threadIdx.x;
  const int tx = t & 31, ty = t >> 5;
  const int brow = blockIdx.y * 32, bcol = blockIdx.x * 32;
  float acc[4] = {0.f, 0.f, 0.f, 0.f};

  for (int k0 = 0; k0 < K_; k0 += 32) {
    for (int l = t; l < 1024; l += 256) {
      const int r = l >> 5, c = l & 31;
      Xs[r][c] = x[(size_t)(brow + r) * K_ + k0 + c];
      const int n = bcol + r;
      const size_t flat = (size_t)n * K_ + (k0 + c);
      const int g = (int)(flat >> 3), j = (int)(flat & 7);
      float wv = cb[idx[g] * 8 + j] * scales[n];
      if (!((signs[g] >> (7 - j)) & 1)) wv = -wv;
      Ws[r][c] = wv;
    }
    __syncthreads();
#pragma unroll
    for (int kk = 0; kk < 32; ++kk) {
      const float wv = Ws[tx][kk];
      acc[0] += Xs[ty][kk] * wv;
      acc[1] += Xs[ty + 8][kk] * wv;
      acc[2] += Xs[ty + 16][kk] * wv;
      acc[3] += Xs[ty + 24][kk] * wv;
    }
    __syncthreads();
  }
#pragma unroll
  for (int q = 0; q < 4; ++q)
    out[(size_t)(brow + ty + 8 * q) * N_ + bcol + tx] = acc[q];
}

// ---------------------------------------------------------------------------
extern "C" void kernel_launch(void* const* d_in, const int* in_sizes, int n_in,
                              void* d_out, int out_size, void* d_ws, size_t ws_size,
                              hipStream_t stream)
{
  const float* x      = (const float*)d_in[0];
  const float* cb     = (const float*)d_in[1];
  const float* scales = (const float*)d_in[2];
  const int*   idx    = (const int*)d_in[3];
  const int*   signs  = (const int*)d_in[4];
  float* out = (float*)d_out;

  const size_t wbytes = (size_t)N_ * K_ * 2;
  const size_t xbytes = (size_t)M_ * K_ * 2;

  if (ws_size >= wbytes + xbytes) {
    unsigned short* Wb = (unsigned short*)d_ws;
    unsigned short* Xb = (unsigned short*)((char*)d_ws + wbytes);
    dequant_w_kernel<<<(N_ * K_ / 8) / 256, 256, 0, stream>>>(cb, scales, idx, signs, Wb);
    cvt_x_kernel<<<(M_ * K_ / 8) / 256, 256, 0, stream>>>(x, Xb);
    gemm256_kernel<<<(M_ / BM) * (N_ / BN), 512, 0, stream>>>(Xb, Wb, out);
  } else {
    fallback_kernel<<<dim3(N_ / 32, M_ / 32), 256, 0, stream>>>(x, cb, scales, idx, signs, out);
  }
}